// Round 9
// baseline (9134.880 us; speedup 1.0000x reference)
//
#include <hip/hip_runtime.h>

#define D_IN   1024
#define D_H    512
#define M_BANK 100
#define BATCH  128
#define NCOL   1224   // 100 rp | 100 wp | 512 c | 512 pre_h
#define NPAD   1280
#define KTOT   1536
#define KSH    4      // split-K partials for the per-step h-GEMM
#define NZH    160    // zh producer jobs: 20 j-tiles x 2 b-tiles x 4 ksplits
#define ZH_TGT 80     // jobs per b-tile

typedef unsigned short u16;
typedef __attribute__((ext_vector_type(8))) short s16x8;
typedef __attribute__((ext_vector_type(4))) float f32x4;

__device__ __forceinline__ u16 f2bf(float f) {
  union { float f; unsigned int u; } v;
  v.f = f;
  unsigned int r = (v.u + 0x7FFFu + ((v.u >> 16) & 1u)) >> 16;
  return (u16)r;
}
__device__ __forceinline__ float bf2f(u16 b) {
  union { unsigned int u; float f; } v;
  v.u = ((unsigned int)b) << 16;
  return v.f;
}

// ---------------------------------------------------------------------------
// k_prep_w: W_bt[j][k] = bf16 of composite W[k][j]  (j-major, for MFMA B-stage)
// ---------------------------------------------------------------------------
__global__ void k_prep_w(const float* __restrict__ W_c,
                         const float* __restrict__ W_rp,
                         const float* __restrict__ W_wp,
                         const float* __restrict__ Wxh,
                         const float* __restrict__ Whh,
                         u16* __restrict__ W_bt) {
  const int j = blockIdx.x;
  const int k = blockIdx.y * 256 + threadIdx.x;
  float v = 0.f;
  if (j < 100)       v = W_rp[(size_t)k * M_BANK + j];
  else if (j < 200)  v = W_wp[(size_t)k * M_BANK + (j - 100)];
  else if (j < 712)  v = W_c[(size_t)k * D_H + (j - 200)];
  else if (j < NCOL) v = (k < D_IN) ? Wxh[(size_t)k * D_H + (j - 712)]
                                    : Whh[(size_t)(k - D_IN) * D_H + (j - 712)];
  W_bt[(size_t)j * KTOT + k] = f2bf(v);
}

__global__ void k_prep_wrh(const float* __restrict__ Wrh,
                           u16* __restrict__ Wrh_bf) {
  const int i = blockIdx.x * 256 + threadIdx.x;
  Wrh_bf[i] = f2bf(Wrh[i]);
}

// ---------------------------------------------------------------------------
// k_zx_mfma: hoisted x-GEMM, bf16 MFMA. zx[(b*CH+tc), j] = x @ W[0:1024, j]
// grid (NPAD/64, BATCH*CH/64), block 256 = 4 waves (2x2 of 32x32)
// ---------------------------------------------------------------------------
__global__ void k_zx_mfma(const float* __restrict__ frames,
                          const u16* __restrict__ W_bt,
                          float* __restrict__ zx,
                          int t0, int CH, int lgCH, int TF) {
  __shared__ u16 Asb[64][40];
  __shared__ u16 Bsb[64][40];
  const int tid  = threadIdx.x;
  const int lane = tid & 63;
  const int wid  = tid >> 6;
  const int wm   = wid >> 1, wn = wid & 1;
  const int j0 = blockIdx.x * 64;
  const int r0 = blockIdx.y * 64;
  const int srow = tid >> 2;
  const int skk  = (tid & 3) * 8;
  const int gr = r0 + srow;
  const int b  = gr >> lgCH;
  const int tc = gr & (CH - 1);
  const float* arow = &frames[((size_t)b * TF + t0 + tc) * D_IN];
  const u16*   brow = &W_bt[(size_t)(j0 + srow) * KTOT];

  f32x4 a00 = {0.f, 0.f, 0.f, 0.f}, a01 = {0.f, 0.f, 0.f, 0.f};
  f32x4 a10 = {0.f, 0.f, 0.f, 0.f}, a11 = {0.f, 0.f, 0.f, 0.f};

  for (int k0 = 0; k0 < D_IN; k0 += 32) {
    const float4 v0 = *reinterpret_cast<const float4*>(&arow[k0 + skk]);
    const float4 v1 = *reinterpret_cast<const float4*>(&arow[k0 + skk + 4]);
    s16x8 a8;
    a8[0] = (short)f2bf(v0.x); a8[1] = (short)f2bf(v0.y);
    a8[2] = (short)f2bf(v0.z); a8[3] = (short)f2bf(v0.w);
    a8[4] = (short)f2bf(v1.x); a8[5] = (short)f2bf(v1.y);
    a8[6] = (short)f2bf(v1.z); a8[7] = (short)f2bf(v1.w);
    *reinterpret_cast<s16x8*>(&Asb[srow][skk]) = a8;
    *reinterpret_cast<s16x8*>(&Bsb[srow][skk]) =
        *reinterpret_cast<const s16x8*>(&brow[k0 + skk]);
    __syncthreads();
    const int ka = (lane >> 4) * 8;
    const s16x8 af0 = *reinterpret_cast<s16x8*>(&Asb[wm * 32 + (lane & 15)][ka]);
    const s16x8 af1 = *reinterpret_cast<s16x8*>(&Asb[wm * 32 + 16 + (lane & 15)][ka]);
    const s16x8 bf0 = *reinterpret_cast<s16x8*>(&Bsb[wn * 32 + (lane & 15)][ka]);
    const s16x8 bf1 = *reinterpret_cast<s16x8*>(&Bsb[wn * 32 + 16 + (lane & 15)][ka]);
    a00 = __builtin_amdgcn_mfma_f32_16x16x32_bf16(af0, bf0, a00, 0, 0, 0);
    a01 = __builtin_amdgcn_mfma_f32_16x16x32_bf16(af0, bf1, a01, 0, 0, 0);
    a10 = __builtin_amdgcn_mfma_f32_16x16x32_bf16(af1, bf0, a10, 0, 0, 0);
    a11 = __builtin_amdgcn_mfma_f32_16x16x32_bf16(af1, bf1, a11, 0, 0, 0);
    __syncthreads();
  }
  const int rb = r0 + wm * 32 + (lane >> 4) * 4;
  const int cb = j0 + wn * 32 + (lane & 15);
#define STORE_ACC(A, MF, NF)                                             \
  {                                                                      \
    _Pragma("unroll")                                                    \
    for (int reg = 0; reg < 4; ++reg)                                    \
      zx[(size_t)(rb + MF * 16 + reg) * NPAD + cb + NF * 16] = A[reg];   \
  }
  STORE_ACC(a00, 0, 0) STORE_ACC(a01, 0, 1) STORE_ACC(a10, 1, 0) STORE_ACC(a11, 1, 1)
#undef STORE_ACC
}

// ---------------------------------------------------------------------------
// k_step2: ONE launch per recurrence step.
//   Blocks 0..159 (t>0): produce one 64x64 zh tile (h_{t-1}@W_h, MFMA, K=128)
//   into zhp, then RELEASE-signal a per-b-tile counter. ALL blocks then
//   ACQUIRE-spin until their b-tile's 80 producer jobs are done, and run
//   phase2 (softmax, c, cw, M2 RMW, h). All 256 blocks co-resident (<=1/CU).
// grid 256, block 512.
// ---------------------------------------------------------------------------
__global__ void __launch_bounds__(512)
k_step2(const float* __restrict__ zx,
        float* __restrict__ zhp,
        const u16* __restrict__ W_bt,
        const u16* __restrict__ Wrh_bf,
        const float* __restrict__ b_rp,
        const float* __restrict__ b_wp,
        const float* __restrict__ b_c,
        const float* __restrict__ bh,
        u16* __restrict__ M2b,
        float* __restrict__ out,
        const u16* __restrict__ h_r,
        u16* __restrict__ h_w,
        int* __restrict__ flags,
        int t, int tc, int CH, int T) {
  // LDS union arena: zh stage needs 2x64x136 u16 = 34816 B; phase2 needs 22144 B
  __shared__ float smem[8704];
  u16* Asb = (u16*)smem;              // [64][136]
  u16* Bsb = Asb + 64 * 136;          // [64][136]
  float* ar_s = smem;                 // [2][100]
  float* aw_s = smem + 200;           // [2][100]
  float* c_s  = smem + 400;           // [2][512]
  float* red  = smem + 1424;          // [2][16][32][4]
  float* smx  = smem + 5520;          // [2][2][2]
  float* ssm  = smem + 5528;          // [2][2][2]

  const int tid  = threadIdx.x;
  const int beta = blockIdx.x;

  // ================= zh producer stage =================
  if (t > 0 && beta < NZH) {
    const int jt = beta % 20;
    const int w  = beta / 20;
    const int bt = w & 1;
    const int kp = w >> 1;
    const int j0 = jt * 64, r0 = bt * 64;
    const int srow = tid >> 3;          // 0..63
    const int sseg = (tid & 7) * 16;    // 8 thr/row x 16 u16
    const u16* arow = &h_r[(size_t)(r0 + srow) * D_H + kp * 128 + sseg];
    const u16* brow = &W_bt[(size_t)(j0 + srow) * KTOT + D_IN + kp * 128 + sseg];
    *reinterpret_cast<s16x8*>(&Asb[srow * 136 + sseg]) =
        *reinterpret_cast<const s16x8*>(&arow[0]);
    *reinterpret_cast<s16x8*>(&Asb[srow * 136 + sseg + 8]) =
        *reinterpret_cast<const s16x8*>(&arow[8]);
    *reinterpret_cast<s16x8*>(&Bsb[srow * 136 + sseg]) =
        *reinterpret_cast<const s16x8*>(&brow[0]);
    *reinterpret_cast<s16x8*>(&Bsb[srow * 136 + sseg + 8]) =
        *reinterpret_cast<const s16x8*>(&brow[8]);
    __syncthreads();

    const int lane = tid & 63;
    const int wid  = tid >> 6;          // 0..7
    const int wm   = wid >> 2;          // 0..1 (32-row half)
    const int wn   = wid & 3;           // 0..3 (16-col slice)
    const int la   = lane & 15;
    f32x4 a0 = {0.f, 0.f, 0.f, 0.f}, a1 = {0.f, 0.f, 0.f, 0.f};
    #pragma unroll
    for (int kk = 0; kk < 4; ++kk) {
      const int ka = kk * 32 + (lane >> 4) * 8;
      const s16x8 af0 = *reinterpret_cast<s16x8*>(&Asb[(wm * 32 + la) * 136 + ka]);
      const s16x8 af1 = *reinterpret_cast<s16x8*>(&Asb[(wm * 32 + 16 + la) * 136 + ka]);
      const s16x8 bf  = *reinterpret_cast<s16x8*>(&Bsb[(wn * 16 + la) * 136 + ka]);
      a0 = __builtin_amdgcn_mfma_f32_16x16x32_bf16(af0, bf, a0, 0, 0, 0);
      a1 = __builtin_amdgcn_mfma_f32_16x16x32_bf16(af1, bf, a1, 0, 0, 0);
    }
    float* zp = &zhp[(size_t)kp * BATCH * NPAD];
    const int rb = r0 + wm * 32 + (lane >> 4) * 4;
    const int cb = j0 + wn * 16 + la;
    #pragma unroll
    for (int reg = 0; reg < 4; ++reg) {
      zp[(size_t)(rb + reg) * NPAD + cb]      = a0[reg];
      zp[(size_t)(rb + 16 + reg) * NPAD + cb] = a1[reg];
    }
    __syncthreads();   // drains stores (vmcnt(0) before barrier)
    if (tid == 0)
      __hip_atomic_fetch_add(&flags[t * 2 + bt], 1,
                             __ATOMIC_RELEASE, __HIP_MEMORY_SCOPE_AGENT);
  }

  // ================= phase2 consumer stage =================
  const int ba   = tid >> 8;            // batch-half 0/1
  const int lane = tid & 31;
  const int p    = beta & 3;            // col-slice 0..3
  const int by   = beta >> 2;           // 0..63
  const int b0   = by * 2;
  const int b_g  = b0 + ba;
  const int s0   = p * 128 + lane * 4;
  const bool hz  = (t > 0);
  const size_t zxrow = (size_t)(b_g * CH + tc) * NPAD;

  if (hz) {
    if (tid == 0) {
      while (__hip_atomic_load(&flags[t * 2 + (by >> 5)],
                               __ATOMIC_ACQUIRE, __HIP_MEMORY_SCOPE_AGENT) < ZH_TGT)
        __builtin_amdgcn_s_sleep(2);
    }
    __syncthreads();
  }

  // ---- softmaxes, fully parallel: u=tid&255, which=u>>7, m=u&127
  {
    const int u     = tid & 255;
    const int which = u >> 7;
    const int m     = u & 127;
    const int wv    = (u >> 6) & 1;
    float l = -1e30f;
    if (m < M_BANK) {
      const int col = which * 100 + m;
      l = (which ? b_wp[m] : b_rp[m]) + zx[zxrow + col];
      if (hz) {
        #pragma unroll
        for (int q = 0; q < KSH; ++q)
          l += zhp[(size_t)(q * BATCH + b_g) * NPAD + col];
      }
    }
    float mx = l;
    #pragma unroll
    for (int o = 32; o; o >>= 1) mx = fmaxf(mx, __shfl_xor(mx, o, 64));
    if ((tid & 63) == 0) smx[ba * 4 + which * 2 + wv] = mx;
    __syncthreads();
    mx = fmaxf(smx[ba * 4 + which * 2], smx[ba * 4 + which * 2 + 1]);
    const float e = (m < M_BANK) ? __expf(l - mx) : 0.f;
    float s = e;
    #pragma unroll
    for (int o = 32; o; o >>= 1) s += __shfl_xor(s, o, 64);
    if ((tid & 63) == 0) ssm[ba * 4 + which * 2 + wv] = s;
    __syncthreads();
    s = ssm[ba * 4 + which * 2] + ssm[ba * 4 + which * 2 + 1];
    if (m < M_BANK) {
      const float a = e / s;
      if (which) aw_s[ba * M_BANK + m] = a;
      else       ar_s[ba * M_BANK + m] = a;
    }
  }
  // ---- stage c = relu(zc + b_c)
  for (int idx = tid; idx < 2 * D_H; idx += 512) {
    const int bb  = idx >> 9;
    const int k   = idx & 511;
    const int bg2 = b0 + bb;
    float v = b_c[k] + zx[(size_t)(bg2 * CH + tc) * NPAD + 200 + k];
    if (hz) {
      #pragma unroll
      for (int q = 0; q < KSH; ++q)
        v += zhp[(size_t)(q * BATCH + bg2) * NPAD + 200 + k];
    }
    c_s[bb * D_H + k] = fmaxf(v, 0.f);
  }
  __syncthreads();

  // ---- cw partials: 16 k-groups of 32, both batches per Wrh(bf16) read
  {
    const int g = tid >> 5;
    float cwa[4] = {};
    float cwb[4] = {};
    const int kbase = g * 32;
    #pragma unroll 8
    for (int kk = 0; kk < 32; ++kk) {
      const int k = kbase + kk;
      const ushort4 w4 = *reinterpret_cast<const ushort4*>(&Wrh_bf[(size_t)k * D_H + s0]);
      const float w0 = bf2f(w4.x), w1 = bf2f(w4.y), w2 = bf2f(w4.z), w3 = bf2f(w4.w);
      const float ca = c_s[k];
      const float cb = c_s[D_H + k];
      cwa[0] += ca * w0; cwa[1] += ca * w1; cwa[2] += ca * w2; cwa[3] += ca * w3;
      cwb[0] += cb * w0; cwb[1] += cb * w1; cwb[2] += cb * w2; cwb[3] += cb * w3;
    }
    #pragma unroll
    for (int j = 0; j < 4; ++j) {
      red[((0 * 16 + g) * 32 + lane) * 4 + j] = cwa[j];
      red[((1 * 16 + g) * 32 + lane) * 4 + j] = cwb[j];
    }
  }
  __syncthreads();
  float cw[4] = {};
  #pragma unroll
  for (int gg = 0; gg < 16; ++gg)
    #pragma unroll
    for (int j = 0; j < 4; ++j) cw[j] += red[((ba * 16 + gg) * 32 + lane) * 4 + j];
  __syncthreads();   // red reused for racc below

  // ---- M2 (bf16) RMW + racc: 8 m-groups per batch
  const int mg    = (tid >> 5) & 7;
  const int mcnt  = (mg < 4) ? 13 : 12;
  const int mbase = (mg < 4) ? mg * 13 : 52 + (mg - 4) * 12;
  float racc[4] = {};
  u16* mp = &M2b[((size_t)b_g * M_BANK + mbase) * D_H + s0];
  for (int mm = 0; mm < mcnt; ++mm) {
    const int m = mbase + mm;
    const ushort4 v4 = *reinterpret_cast<const ushort4*>(mp);
    const float v0 = bf2f(v4.x), v1 = bf2f(v4.y), v2 = bf2f(v4.z), v3 = bf2f(v4.w);
    const float a = ar_s[ba * M_BANK + m];
    const float w = aw_s[ba * M_BANK + m];
    racc[0] += a * v0; racc[1] += a * v1; racc[2] += a * v2; racc[3] += a * v3;
    ushort4 nv;
    nv.x = f2bf(w * cw[0] + (1.f - w) * v0);
    nv.y = f2bf(w * cw[1] + (1.f - w) * v1);
    nv.z = f2bf(w * cw[2] + (1.f - w) * v2);
    nv.w = f2bf(w * cw[3] + (1.f - w) * v3);
    *reinterpret_cast<ushort4*>(mp) = nv;
    mp += D_H;
  }
  #pragma unroll
  for (int j = 0; j < 4; ++j) red[((ba * 16 + mg) * 32 + lane) * 4 + j] = racc[j];
  __syncthreads();

  // ---- h epilogue: 32 lanes per batch-half cover the 128-col slice
  if ((tid & 255) < 32) {
    float ph[4];
    const float4 vb = *reinterpret_cast<const float4*>(&bh[s0]);
    const float4 px = *reinterpret_cast<const float4*>(&zx[zxrow + 712 + s0]);
    ph[0] = vb.x + px.x; ph[1] = vb.y + px.y;
    ph[2] = vb.z + px.z; ph[3] = vb.w + px.w;
    #pragma unroll
    for (int gg = 0; gg < 8; ++gg)
      #pragma unroll
      for (int j = 0; j < 4; ++j) ph[j] += red[((ba * 16 + gg) * 32 + lane) * 4 + j];
    if (hz) {
      #pragma unroll
      for (int q = 0; q < KSH; ++q) {
        const float4 pz = *reinterpret_cast<const float4*>(
            &zhp[(size_t)(q * BATCH + b_g) * NPAD + 712 + s0]);
        ph[0] += pz.x; ph[1] += pz.y; ph[2] += pz.z; ph[3] += pz.w;
      }
    }
    float4 h;
    h.x = fmaxf(ph[0], 0.f); h.y = fmaxf(ph[1], 0.f);
    h.z = fmaxf(ph[2], 0.f); h.w = fmaxf(ph[3], 0.f);
    *reinterpret_cast<float4*>(&out[((size_t)b_g * T + t) * D_H + s0]) = h;
    ushort4 hb;
    hb.x = f2bf(h.x); hb.y = f2bf(h.y); hb.z = f2bf(h.z); hb.w = f2bf(h.w);
    *reinterpret_cast<ushort4*>(&h_w[(size_t)b_g * D_H + s0]) = hb;
  }
}

// ---------------------------------------------------------------------------
extern "C" void kernel_launch(void* const* d_in, const int* in_sizes, int n_in,
                              void* d_out, int out_size, void* d_ws, size_t ws_size,
                              hipStream_t stream) {
  const float* frames = (const float*)d_in[0];
  const float* W_c    = (const float*)d_in[1];
  const float* b_c    = (const float*)d_in[2];
  const float* W_rp   = (const float*)d_in[3];
  const float* b_rp   = (const float*)d_in[4];
  const float* W_wp   = (const float*)d_in[5];
  const float* b_wp   = (const float*)d_in[6];
  const float* Wxh    = (const float*)d_in[7];
  const float* Wrh    = (const float*)d_in[8];
  const float* Whh    = (const float*)d_in[9];
  const float* bh     = (const float*)d_in[10];
  float* out = (float*)d_out;

  const int TF = in_sizes[0] / (BATCH * D_IN);
  const int T  = out_size / (BATCH * D_H);

  // element counts in float-equivalents (u16 regions counted /2)
  const size_t M2B_FL = (size_t)BATCH * M_BANK * D_H / 2;   // 13.1 MB
  const size_t ZHP_FL = (size_t)KSH * BATCH * NPAD;         // 2.6 MB
  const size_t WBT_FL = (size_t)NPAD * KTOT / 2;            // 3.9 MB
  const size_t WRH_FL = (size_t)D_H * D_H / 2;              // 0.5 MB
  const size_t HBF_FL = (size_t)BATCH * D_H;                // 2 bufs, u16 -> fl
  const size_t FLG_FL = 2048;                               // flags: T*2 ints max

  u16*   M2b = (u16*)d_ws;
  float* zhp = (float*)d_ws + M2B_FL;
  float* zx  = zhp + ZHP_FL;

  int CH = 32, lgCH = 5;
  while (CH > 1 &&
         ((M2B_FL + ZHP_FL + WBT_FL + WRH_FL + HBF_FL + FLG_FL +
           (size_t)BATCH * CH * NPAD) * sizeof(float) > ws_size ||
          (T % CH) != 0)) {
    CH >>= 1; --lgCH;
  }

  u16* W_bt   = (u16*)(zx + (size_t)BATCH * CH * NPAD);
  u16* Wrh_bf = W_bt + (size_t)NPAD * KTOT;
  u16* hbuf0  = Wrh_bf + (size_t)D_H * D_H;
  u16* hbuf1  = hbuf0 + (size_t)BATCH * D_H;
  int* flags  = (int*)(hbuf1 + (size_t)BATCH * D_H);
  u16* hb[2]  = {hbuf0, hbuf1};

  hipMemsetAsync(M2b, 0, M2B_FL * sizeof(float), stream);
  hipMemsetAsync(flags, 0, (size_t)2 * T * sizeof(int), stream);
  k_prep_w<<<dim3(NPAD, KTOT / 256), 256, 0, stream>>>(W_c, W_rp, W_wp, Wxh, Whh, W_bt);
  k_prep_wrh<<<dim3(D_H * D_H / 256), 256, 0, stream>>>(Wrh, Wrh_bf);

  for (int t0 = 0; t0 < T; t0 += CH) {
    k_zx_mfma<<<dim3(NPAD / 64, BATCH * CH / 64), 256, 0, stream>>>(
        frames, W_bt, zx, t0, CH, lgCH, TF);
    for (int t = t0; t < t0 + CH; ++t) {
      // zh reads h written at launch t-1 into hb[t&1]; phase2 writes hb[(t+1)&1]
      k_step2<<<256, 512, 0, stream>>>(
          zx, zhp, W_bt, Wrh_bf, b_rp, b_wp, b_c, bh, M2b, out,
          hb[t & 1], hb[(t + 1) & 1], flags, t, t - t0, CH, T);
    }
  }
}

// Round 10
// 6337.868 us; speedup vs baseline: 1.4413x; 1.4413x over previous
//
#include <hip/hip_runtime.h>

#define D_IN   1024
#define D_H    512
#define M_BANK 100
#define BATCH  128
#define NCOL   1224   // 100 rp | 100 wp | 512 c | 512 pre_h
#define NPAD   1280
#define KTOT   1536
#define KSH    4      // split-K partials for the per-step h-GEMM
#define NZH    160    // zh producer jobs: 20 j-tiles x 2 b-tiles x 4 ksplits

typedef unsigned short u16;
typedef __attribute__((ext_vector_type(8))) short s16x8;
typedef __attribute__((ext_vector_type(4))) float f32x4;

__device__ __forceinline__ u16 f2bf(float f) {
  union { float f; unsigned int u; } v;
  v.f = f;
  unsigned int r = (v.u + 0x7FFFu + ((v.u >> 16) & 1u)) >> 16;
  return (u16)r;
}
__device__ __forceinline__ float bf2f(u16 b) {
  union { unsigned int u; float f; } v;
  v.u = ((unsigned int)b) << 16;
  return v.f;
}

// ---------------------------------------------------------------------------
// k_prep_w: W_bt[j][k] = bf16 of composite W[k][j]  (j-major, for MFMA B-stage)
// ---------------------------------------------------------------------------
__global__ void k_prep_w(const float* __restrict__ W_c,
                         const float* __restrict__ W_rp,
                         const float* __restrict__ W_wp,
                         const float* __restrict__ Wxh,
                         const float* __restrict__ Whh,
                         u16* __restrict__ W_bt) {
  const int j = blockIdx.x;
  const int k = blockIdx.y * 256 + threadIdx.x;
  float v = 0.f;
  if (j < 100)       v = W_rp[(size_t)k * M_BANK + j];
  else if (j < 200)  v = W_wp[(size_t)k * M_BANK + (j - 100)];
  else if (j < 712)  v = W_c[(size_t)k * D_H + (j - 200)];
  else if (j < NCOL) v = (k < D_IN) ? Wxh[(size_t)k * D_H + (j - 712)]
                                    : Whh[(size_t)(k - D_IN) * D_H + (j - 712)];
  W_bt[(size_t)j * KTOT + k] = f2bf(v);
}

__global__ void k_prep_wrh(const float* __restrict__ Wrh,
                           u16* __restrict__ Wrh_bf) {
  const int i = blockIdx.x * 256 + threadIdx.x;
  Wrh_bf[i] = f2bf(Wrh[i]);
}

// ---------------------------------------------------------------------------
// k_zx_mfma: hoisted x-GEMM, bf16 MFMA. zx[(b*CH+tc), j] = x @ W[0:1024, j]
// grid (NPAD/64, BATCH*CH/64), block 256 = 4 waves (2x2 of 32x32)
// ---------------------------------------------------------------------------
__global__ void k_zx_mfma(const float* __restrict__ frames,
                          const u16* __restrict__ W_bt,
                          float* __restrict__ zx,
                          int t0, int CH, int lgCH, int TF) {
  __shared__ u16 Asb[64][40];
  __shared__ u16 Bsb[64][40];
  const int tid  = threadIdx.x;
  const int lane = tid & 63;
  const int wid  = tid >> 6;
  const int wm   = wid >> 1, wn = wid & 1;
  const int j0 = blockIdx.x * 64;
  const int r0 = blockIdx.y * 64;
  const int srow = tid >> 2;
  const int skk  = (tid & 3) * 8;
  const int gr = r0 + srow;
  const int b  = gr >> lgCH;
  const int tc = gr & (CH - 1);
  const float* arow = &frames[((size_t)b * TF + t0 + tc) * D_IN];
  const u16*   brow = &W_bt[(size_t)(j0 + srow) * KTOT];

  f32x4 a00 = {0.f, 0.f, 0.f, 0.f}, a01 = {0.f, 0.f, 0.f, 0.f};
  f32x4 a10 = {0.f, 0.f, 0.f, 0.f}, a11 = {0.f, 0.f, 0.f, 0.f};

  for (int k0 = 0; k0 < D_IN; k0 += 32) {
    const float4 v0 = *reinterpret_cast<const float4*>(&arow[k0 + skk]);
    const float4 v1 = *reinterpret_cast<const float4*>(&arow[k0 + skk + 4]);
    s16x8 a8;
    a8[0] = (short)f2bf(v0.x); a8[1] = (short)f2bf(v0.y);
    a8[2] = (short)f2bf(v0.z); a8[3] = (short)f2bf(v0.w);
    a8[4] = (short)f2bf(v1.x); a8[5] = (short)f2bf(v1.y);
    a8[6] = (short)f2bf(v1.z); a8[7] = (short)f2bf(v1.w);
    *reinterpret_cast<s16x8*>(&Asb[srow][skk]) = a8;
    *reinterpret_cast<s16x8*>(&Bsb[srow][skk]) =
        *reinterpret_cast<const s16x8*>(&brow[k0 + skk]);
    __syncthreads();
    const int ka = (lane >> 4) * 8;
    const s16x8 af0 = *reinterpret_cast<s16x8*>(&Asb[wm * 32 + (lane & 15)][ka]);
    const s16x8 af1 = *reinterpret_cast<s16x8*>(&Asb[wm * 32 + 16 + (lane & 15)][ka]);
    const s16x8 bf0 = *reinterpret_cast<s16x8*>(&Bsb[wn * 32 + (lane & 15)][ka]);
    const s16x8 bf1 = *reinterpret_cast<s16x8*>(&Bsb[wn * 32 + 16 + (lane & 15)][ka]);
    a00 = __builtin_amdgcn_mfma_f32_16x16x32_bf16(af0, bf0, a00, 0, 0, 0);
    a01 = __builtin_amdgcn_mfma_f32_16x16x32_bf16(af0, bf1, a01, 0, 0, 0);
    a10 = __builtin_amdgcn_mfma_f32_16x16x32_bf16(af1, bf0, a10, 0, 0, 0);
    a11 = __builtin_amdgcn_mfma_f32_16x16x32_bf16(af1, bf1, a11, 0, 0, 0);
    __syncthreads();
  }
  const int rb = r0 + wm * 32 + (lane >> 4) * 4;
  const int cb = j0 + wn * 32 + (lane & 15);
#define STORE_ACC(A, MF, NF)                                             \
  {                                                                      \
    _Pragma("unroll")                                                    \
    for (int reg = 0; reg < 4; ++reg)                                    \
      zx[(size_t)(rb + MF * 16 + reg) * NPAD + cb + NF * 16] = A[reg];   \
  }
  STORE_ACC(a00, 0, 0) STORE_ACC(a01, 0, 1) STORE_ACC(a10, 1, 0) STORE_ACC(a11, 1, 1)
#undef STORE_ACC
}

// ---------------------------------------------------------------------------
// k_step2: ONE launch per recurrence step.
//   Blocks 0..159 (t>0): produce one 64x64 zh tile (h_{t-1}@W_h, MFMA, K=128)
//   into zhp; arrivals counted with fetch_add(ACQ_REL); the LAST arrival
//   resets the counter and release-stores gen = t (single line flip).
//   All blocks then poll gen with RELAXED loads (+one acquire fence on exit)
//   and run phase2. All 256 blocks co-resident (1/CU).
// grid 256, block 512.
// ---------------------------------------------------------------------------
__global__ void __launch_bounds__(512)
k_step2(const float* __restrict__ zx,
        float* __restrict__ zhp,
        const u16* __restrict__ W_bt,
        const u16* __restrict__ Wrh_bf,
        const float* __restrict__ b_rp,
        const float* __restrict__ b_wp,
        const float* __restrict__ b_c,
        const float* __restrict__ bh,
        u16* __restrict__ M2b,
        float* __restrict__ out,
        const u16* __restrict__ h_r,
        u16* __restrict__ h_w,
        int* __restrict__ cnt,
        int* __restrict__ gen,
        int t, int tc, int CH, int T) {
  // LDS union arena: zh stage needs 2x64x136 u16 = 34816 B; phase2 needs 22144 B
  __shared__ float smem[8704];
  u16* Asb = (u16*)smem;              // [64][136]
  u16* Bsb = Asb + 64 * 136;          // [64][136]
  float* ar_s = smem;                 // [2][100]
  float* aw_s = smem + 200;           // [2][100]
  float* c_s  = smem + 400;           // [2][512]
  float* red  = smem + 1424;          // [2][16][32][4]
  float* smx  = smem + 5520;          // [2][2][2]
  float* ssm  = smem + 5528;          // [2][2][2]

  const int tid  = threadIdx.x;
  const int beta = blockIdx.x;

  // ================= zh producer stage =================
  if (t > 0 && beta < NZH) {
    const int jt = beta % 20;
    const int w  = beta / 20;
    const int bt = w & 1;
    const int kp = w >> 1;
    const int j0 = jt * 64, r0 = bt * 64;
    const int srow = tid >> 3;          // 0..63
    const int sseg = (tid & 7) * 16;    // 8 thr/row x 16 u16
    const u16* arow = &h_r[(size_t)(r0 + srow) * D_H + kp * 128 + sseg];
    const u16* brow = &W_bt[(size_t)(j0 + srow) * KTOT + D_IN + kp * 128 + sseg];
    *reinterpret_cast<s16x8*>(&Asb[srow * 136 + sseg]) =
        *reinterpret_cast<const s16x8*>(&arow[0]);
    *reinterpret_cast<s16x8*>(&Asb[srow * 136 + sseg + 8]) =
        *reinterpret_cast<const s16x8*>(&arow[8]);
    *reinterpret_cast<s16x8*>(&Bsb[srow * 136 + sseg]) =
        *reinterpret_cast<const s16x8*>(&brow[0]);
    *reinterpret_cast<s16x8*>(&Bsb[srow * 136 + sseg + 8]) =
        *reinterpret_cast<const s16x8*>(&brow[8]);
    __syncthreads();

    const int lane = tid & 63;
    const int wid  = tid >> 6;          // 0..7
    const int wm   = wid >> 2;          // 0..1 (32-row half)
    const int wn   = wid & 3;           // 0..3 (16-col slice)
    const int la   = lane & 15;
    f32x4 a0 = {0.f, 0.f, 0.f, 0.f}, a1 = {0.f, 0.f, 0.f, 0.f};
    #pragma unroll
    for (int kk = 0; kk < 4; ++kk) {
      const int ka = kk * 32 + (lane >> 4) * 8;
      const s16x8 af0 = *reinterpret_cast<s16x8*>(&Asb[(wm * 32 + la) * 136 + ka]);
      const s16x8 af1 = *reinterpret_cast<s16x8*>(&Asb[(wm * 32 + 16 + la) * 136 + ka]);
      const s16x8 bf  = *reinterpret_cast<s16x8*>(&Bsb[(wn * 16 + la) * 136 + ka]);
      a0 = __builtin_amdgcn_mfma_f32_16x16x32_bf16(af0, bf, a0, 0, 0, 0);
      a1 = __builtin_amdgcn_mfma_f32_16x16x32_bf16(af1, bf, a1, 0, 0, 0);
    }
    float* zp = &zhp[(size_t)kp * BATCH * NPAD];
    const int rb = r0 + wm * 32 + (lane >> 4) * 4;
    const int cb = j0 + wn * 16 + la;
    #pragma unroll
    for (int reg = 0; reg < 4; ++reg) {
      zp[(size_t)(rb + reg) * NPAD + cb]      = a0[reg];
      zp[(size_t)(rb + 16 + reg) * NPAD + cb] = a1[reg];
    }
    __syncthreads();   // drains this block's zhp stores (vmcnt(0) before barrier)
    if (tid == 0) {
      const int a = __hip_atomic_fetch_add(cnt, 1, __ATOMIC_ACQ_REL,
                                           __HIP_MEMORY_SCOPE_AGENT);
      if (a == NZH - 1) {
        __hip_atomic_store(cnt, 0, __ATOMIC_RELAXED, __HIP_MEMORY_SCOPE_AGENT);
        __hip_atomic_store(gen, t, __ATOMIC_RELEASE, __HIP_MEMORY_SCOPE_AGENT);
      }
    }
  }

  // ================= phase2 consumer stage =================
  const int ba   = tid >> 8;            // batch-half 0/1
  const int lane = tid & 31;
  const int p    = beta & 3;            // col-slice 0..3
  const int by   = beta >> 2;           // 0..63
  const int b0   = by * 2;
  const int b_g  = b0 + ba;
  const int s0   = p * 128 + lane * 4;
  const bool hz  = (t > 0);
  const size_t zxrow = (size_t)(b_g * CH + tc) * NPAD;

  if (hz) {
    if (tid == 0) {
      while (__hip_atomic_load(gen, __ATOMIC_RELAXED, __HIP_MEMORY_SCOPE_AGENT) < t)
        __builtin_amdgcn_s_sleep(8);
      __builtin_amdgcn_fence(__ATOMIC_ACQUIRE, "agent");
    }
    __syncthreads();
  }

  // ---- softmaxes, fully parallel: u=tid&255, which=u>>7, m=u&127
  {
    const int u     = tid & 255;
    const int which = u >> 7;
    const int m     = u & 127;
    const int wv    = (u >> 6) & 1;
    float l = -1e30f;
    if (m < M_BANK) {
      const int col = which * 100 + m;
      l = (which ? b_wp[m] : b_rp[m]) + zx[zxrow + col];
      if (hz) {
        #pragma unroll
        for (int q = 0; q < KSH; ++q)
          l += zhp[(size_t)(q * BATCH + b_g) * NPAD + col];
      }
    }
    float mx = l;
    #pragma unroll
    for (int o = 32; o; o >>= 1) mx = fmaxf(mx, __shfl_xor(mx, o, 64));
    if ((tid & 63) == 0) smx[ba * 4 + which * 2 + wv] = mx;
    __syncthreads();
    mx = fmaxf(smx[ba * 4 + which * 2], smx[ba * 4 + which * 2 + 1]);
    const float e = (m < M_BANK) ? __expf(l - mx) : 0.f;
    float s = e;
    #pragma unroll
    for (int o = 32; o; o >>= 1) s += __shfl_xor(s, o, 64);
    if ((tid & 63) == 0) ssm[ba * 4 + which * 2 + wv] = s;
    __syncthreads();
    s = ssm[ba * 4 + which * 2] + ssm[ba * 4 + which * 2 + 1];
    if (m < M_BANK) {
      const float a = e / s;
      if (which) aw_s[ba * M_BANK + m] = a;
      else       ar_s[ba * M_BANK + m] = a;
    }
  }
  // ---- stage c = relu(zc + b_c)
  for (int idx = tid; idx < 2 * D_H; idx += 512) {
    const int bb  = idx >> 9;
    const int k   = idx & 511;
    const int bg2 = b0 + bb;
    float v = b_c[k] + zx[(size_t)(bg2 * CH + tc) * NPAD + 200 + k];
    if (hz) {
      #pragma unroll
      for (int q = 0; q < KSH; ++q)
        v += zhp[(size_t)(q * BATCH + bg2) * NPAD + 200 + k];
    }
    c_s[bb * D_H + k] = fmaxf(v, 0.f);
  }
  __syncthreads();

  // ---- cw partials: 16 k-groups of 32, both batches per Wrh(bf16) read
  {
    const int g = tid >> 5;
    float cwa[4] = {};
    float cwb[4] = {};
    const int kbase = g * 32;
    #pragma unroll 8
    for (int kk = 0; kk < 32; ++kk) {
      const int k = kbase + kk;
      const ushort4 w4 = *reinterpret_cast<const ushort4*>(&Wrh_bf[(size_t)k * D_H + s0]);
      const float w0 = bf2f(w4.x), w1 = bf2f(w4.y), w2 = bf2f(w4.z), w3 = bf2f(w4.w);
      const float ca = c_s[k];
      const float cb = c_s[D_H + k];
      cwa[0] += ca * w0; cwa[1] += ca * w1; cwa[2] += ca * w2; cwa[3] += ca * w3;
      cwb[0] += cb * w0; cwb[1] += cb * w1; cwb[2] += cb * w2; cwb[3] += cb * w3;
    }
    #pragma unroll
    for (int j = 0; j < 4; ++j) {
      red[((0 * 16 + g) * 32 + lane) * 4 + j] = cwa[j];
      red[((1 * 16 + g) * 32 + lane) * 4 + j] = cwb[j];
    }
  }
  __syncthreads();
  float cw[4] = {};
  #pragma unroll
  for (int gg = 0; gg < 16; ++gg)
    #pragma unroll
    for (int j = 0; j < 4; ++j) cw[j] += red[((ba * 16 + gg) * 32 + lane) * 4 + j];
  __syncthreads();   // red reused for racc below

  // ---- M2 (bf16) RMW + racc: 8 m-groups per batch
  const int mg    = (tid >> 5) & 7;
  const int mcnt  = (mg < 4) ? 13 : 12;
  const int mbase = (mg < 4) ? mg * 13 : 52 + (mg - 4) * 12;
  float racc[4] = {};
  u16* mp = &M2b[((size_t)b_g * M_BANK + mbase) * D_H + s0];
  for (int mm = 0; mm < mcnt; ++mm) {
    const int m = mbase + mm;
    const ushort4 v4 = *reinterpret_cast<const ushort4*>(mp);
    const float v0 = bf2f(v4.x), v1 = bf2f(v4.y), v2 = bf2f(v4.z), v3 = bf2f(v4.w);
    const float a = ar_s[ba * M_BANK + m];
    const float w = aw_s[ba * M_BANK + m];
    racc[0] += a * v0; racc[1] += a * v1; racc[2] += a * v2; racc[3] += a * v3;
    ushort4 nv;
    nv.x = f2bf(w * cw[0] + (1.f - w) * v0);
    nv.y = f2bf(w * cw[1] + (1.f - w) * v1);
    nv.z = f2bf(w * cw[2] + (1.f - w) * v2);
    nv.w = f2bf(w * cw[3] + (1.f - w) * v3);
    *reinterpret_cast<ushort4*>(mp) = nv;
    mp += D_H;
  }
  #pragma unroll
  for (int j = 0; j < 4; ++j) red[((ba * 16 + mg) * 32 + lane) * 4 + j] = racc[j];
  __syncthreads();

  // ---- h epilogue: 32 lanes per batch-half cover the 128-col slice
  if ((tid & 255) < 32) {
    float ph[4];
    const float4 vb = *reinterpret_cast<const float4*>(&bh[s0]);
    const float4 px = *reinterpret_cast<const float4*>(&zx[zxrow + 712 + s0]);
    ph[0] = vb.x + px.x; ph[1] = vb.y + px.y;
    ph[2] = vb.z + px.z; ph[3] = vb.w + px.w;
    #pragma unroll
    for (int gg = 0; gg < 8; ++gg)
      #pragma unroll
      for (int j = 0; j < 4; ++j) ph[j] += red[((ba * 16 + gg) * 32 + lane) * 4 + j];
    if (hz) {
      #pragma unroll
      for (int q = 0; q < KSH; ++q) {
        const float4 pz = *reinterpret_cast<const float4*>(
            &zhp[(size_t)(q * BATCH + b_g) * NPAD + 712 + s0]);
        ph[0] += pz.x; ph[1] += pz.y; ph[2] += pz.z; ph[3] += pz.w;
      }
    }
    float4 h;
    h.x = fmaxf(ph[0], 0.f); h.y = fmaxf(ph[1], 0.f);
    h.z = fmaxf(ph[2], 0.f); h.w = fmaxf(ph[3], 0.f);
    *reinterpret_cast<float4*>(&out[((size_t)b_g * T + t) * D_H + s0]) = h;
    ushort4 hb;
    hb.x = f2bf(h.x); hb.y = f2bf(h.y); hb.z = f2bf(h.z); hb.w = f2bf(h.w);
    *reinterpret_cast<ushort4*>(&h_w[(size_t)b_g * D_H + s0]) = hb;
  }
}

// ---------------------------------------------------------------------------
extern "C" void kernel_launch(void* const* d_in, const int* in_sizes, int n_in,
                              void* d_out, int out_size, void* d_ws, size_t ws_size,
                              hipStream_t stream) {
  const float* frames = (const float*)d_in[0];
  const float* W_c    = (const float*)d_in[1];
  const float* b_c    = (const float*)d_in[2];
  const float* W_rp   = (const float*)d_in[3];
  const float* b_rp   = (const float*)d_in[4];
  const float* W_wp   = (const float*)d_in[5];
  const float* b_wp   = (const float*)d_in[6];
  const float* Wxh    = (const float*)d_in[7];
  const float* Wrh    = (const float*)d_in[8];
  const float* Whh    = (const float*)d_in[9];
  const float* bh     = (const float*)d_in[10];
  float* out = (float*)d_out;

  const int TF = in_sizes[0] / (BATCH * D_IN);
  const int T  = out_size / (BATCH * D_H);

  // element counts in float-equivalents (u16 regions counted /2)
  const size_t M2B_FL = (size_t)BATCH * M_BANK * D_H / 2;   // 13.1 MB
  const size_t ZHP_FL = (size_t)KSH * BATCH * NPAD;         // 2.6 MB
  const size_t WBT_FL = (size_t)NPAD * KTOT / 2;            // 3.9 MB
  const size_t WRH_FL = (size_t)D_H * D_H / 2;              // 0.5 MB
  const size_t HBF_FL = (size_t)BATCH * D_H;                // 2 bufs, u16 -> fl
  const size_t SYN_FL = 64;                                 // cnt/gen lines

  u16*   M2b = (u16*)d_ws;
  float* zhp = (float*)d_ws + M2B_FL;
  float* zx  = zhp + ZHP_FL;

  int CH = 32, lgCH = 5;
  while (CH > 1 &&
         ((M2B_FL + ZHP_FL + WBT_FL + WRH_FL + HBF_FL + SYN_FL +
           (size_t)BATCH * CH * NPAD) * sizeof(float) > ws_size ||
          (T % CH) != 0)) {
    CH >>= 1; --lgCH;
  }

  u16* W_bt   = (u16*)(zx + (size_t)BATCH * CH * NPAD);
  u16* Wrh_bf = W_bt + (size_t)NPAD * KTOT;
  u16* hbuf0  = Wrh_bf + (size_t)D_H * D_H;
  u16* hbuf1  = hbuf0 + (size_t)BATCH * D_H;
  int* sync   = (int*)(hbuf1 + (size_t)BATCH * D_H);
  int* cnt    = sync;        // own 128B line
  int* gen    = sync + 32;   // separate 128B line
  u16* hb[2]  = {hbuf0, hbuf1};

  hipMemsetAsync(M2b, 0, M2B_FL * sizeof(float), stream);
  hipMemsetAsync(sync, 0, 64 * sizeof(int), stream);   // cnt=0, gen=0 (waits start at t>=1)
  k_prep_w<<<dim3(NPAD, KTOT / 256), 256, 0, stream>>>(W_c, W_rp, W_wp, Wxh, Whh, W_bt);
  k_prep_wrh<<<dim3(D_H * D_H / 256), 256, 0, stream>>>(Wrh, Wrh_bf);

  for (int t0 = 0; t0 < T; t0 += CH) {
    k_zx_mfma<<<dim3(NPAD / 64, BATCH * CH / 64), 256, 0, stream>>>(
        frames, W_bt, zx, t0, CH, lgCH, TF);
    for (int t = t0; t < t0 + CH; ++t) {
      // zh reads h written at launch t-1 into hb[t&1]; phase2 writes hb[(t+1)&1]
      k_step2<<<256, 512, 0, stream>>>(
          zx, zhp, W_bt, Wrh_bf, b_rp, b_wp, b_c, bh, M2b, out,
          hb[t & 1], hb[(t + 1) & 1], cnt, gen, t, t - t0, CH, T);
    }
  }
}

// Round 11
// 6078.560 us; speedup vs baseline: 1.5028x; 1.0427x over previous
//
#include <hip/hip_runtime.h>

#define D_IN   1024
#define D_H    512
#define M_BANK 100
#define BATCH  128
#define NCOL   1224   // 100 rp | 100 wp | 512 c | 512 pre_h
#define NPAD   1280
#define KTOT   1536
#define KSH    4      // split-K partials for the per-step h-GEMM

typedef unsigned short u16;
typedef __attribute__((ext_vector_type(8))) short s16x8;
typedef __attribute__((ext_vector_type(4))) float f32x4;

__device__ __forceinline__ u16 f2bf(float f) {
  union { float f; unsigned int u; } v;
  v.f = f;
  unsigned int r = (v.u + 0x7FFFu + ((v.u >> 16) & 1u)) >> 16;
  return (u16)r;
}
__device__ __forceinline__ float bf2f(u16 b) {
  union { unsigned int u; float f; } v;
  v.u = ((unsigned int)b) << 16;
  return v.f;
}

// ---------------------------------------------------------------------------
// k_prep_w: W_bt[j][k] = bf16 of composite W[k][j]  (j-major, for MFMA B-stage)
//   cols [0,100)=W_rp [100,200)=W_wp [200,712)=W_c [712,1224)=Wxh/Whh else 0
// ---------------------------------------------------------------------------
__global__ void k_prep_w(const float* __restrict__ W_c,
                         const float* __restrict__ W_rp,
                         const float* __restrict__ W_wp,
                         const float* __restrict__ Wxh,
                         const float* __restrict__ Whh,
                         u16* __restrict__ W_bt) {
  const int j = blockIdx.x;
  const int k = blockIdx.y * 256 + threadIdx.x;
  float v = 0.f;
  if (j < 100)       v = W_rp[(size_t)k * M_BANK + j];
  else if (j < 200)  v = W_wp[(size_t)k * M_BANK + (j - 100)];
  else if (j < 712)  v = W_c[(size_t)k * D_H + (j - 200)];
  else if (j < NCOL) v = (k < D_IN) ? Wxh[(size_t)k * D_H + (j - 712)]
                                    : Whh[(size_t)(k - D_IN) * D_H + (j - 712)];
  W_bt[(size_t)j * KTOT + k] = f2bf(v);
}

__global__ void k_prep_wrh(const float* __restrict__ Wrh,
                           u16* __restrict__ Wrh_bf) {
  const int i = blockIdx.x * 256 + threadIdx.x;
  Wrh_bf[i] = f2bf(Wrh[i]);
}

// ---------------------------------------------------------------------------
// k_zx_mfma: hoisted x-GEMM, bf16 MFMA. zx[(b*CH+tc), j] = x @ W[0:1024, j]
// grid (NPAD/64, BATCH*CH/64), block 256 = 4 waves (2x2 of 32x32)
// ---------------------------------------------------------------------------
__global__ void k_zx_mfma(const float* __restrict__ frames,
                          const u16* __restrict__ W_bt,
                          float* __restrict__ zx,
                          int t0, int CH, int lgCH, int TF) {
  __shared__ u16 Asb[64][40];
  __shared__ u16 Bsb[64][40];
  const int tid  = threadIdx.x;
  const int lane = tid & 63;
  const int wid  = tid >> 6;
  const int wm   = wid >> 1, wn = wid & 1;
  const int j0 = blockIdx.x * 64;
  const int r0 = blockIdx.y * 64;
  const int srow = tid >> 2;
  const int skk  = (tid & 3) * 8;
  const int gr = r0 + srow;
  const int b  = gr >> lgCH;
  const int tc = gr & (CH - 1);
  const float* arow = &frames[((size_t)b * TF + t0 + tc) * D_IN];
  const u16*   brow = &W_bt[(size_t)(j0 + srow) * KTOT];

  f32x4 a00 = {0.f, 0.f, 0.f, 0.f}, a01 = {0.f, 0.f, 0.f, 0.f};
  f32x4 a10 = {0.f, 0.f, 0.f, 0.f}, a11 = {0.f, 0.f, 0.f, 0.f};

  for (int k0 = 0; k0 < D_IN; k0 += 32) {
    const float4 v0 = *reinterpret_cast<const float4*>(&arow[k0 + skk]);
    const float4 v1 = *reinterpret_cast<const float4*>(&arow[k0 + skk + 4]);
    s16x8 a8;
    a8[0] = (short)f2bf(v0.x); a8[1] = (short)f2bf(v0.y);
    a8[2] = (short)f2bf(v0.z); a8[3] = (short)f2bf(v0.w);
    a8[4] = (short)f2bf(v1.x); a8[5] = (short)f2bf(v1.y);
    a8[6] = (short)f2bf(v1.z); a8[7] = (short)f2bf(v1.w);
    *reinterpret_cast<s16x8*>(&Asb[srow][skk]) = a8;
    *reinterpret_cast<s16x8*>(&Bsb[srow][skk]) =
        *reinterpret_cast<const s16x8*>(&brow[k0 + skk]);
    __syncthreads();
    const int ka = (lane >> 4) * 8;
    const s16x8 af0 = *reinterpret_cast<s16x8*>(&Asb[wm * 32 + (lane & 15)][ka]);
    const s16x8 af1 = *reinterpret_cast<s16x8*>(&Asb[wm * 32 + 16 + (lane & 15)][ka]);
    const s16x8 bf0 = *reinterpret_cast<s16x8*>(&Bsb[wn * 32 + (lane & 15)][ka]);
    const s16x8 bf1 = *reinterpret_cast<s16x8*>(&Bsb[wn * 32 + 16 + (lane & 15)][ka]);
    a00 = __builtin_amdgcn_mfma_f32_16x16x32_bf16(af0, bf0, a00, 0, 0, 0);
    a01 = __builtin_amdgcn_mfma_f32_16x16x32_bf16(af0, bf1, a01, 0, 0, 0);
    a10 = __builtin_amdgcn_mfma_f32_16x16x32_bf16(af1, bf0, a10, 0, 0, 0);
    a11 = __builtin_amdgcn_mfma_f32_16x16x32_bf16(af1, bf1, a11, 0, 0, 0);
    __syncthreads();
  }
  const int rb = r0 + wm * 32 + (lane >> 4) * 4;
  const int cb = j0 + wn * 32 + (lane & 15);
#define STORE_ACC(A, MF, NF)                                             \
  {                                                                      \
    _Pragma("unroll")                                                    \
    for (int reg = 0; reg < 4; ++reg)                                    \
      zx[(size_t)(rb + MF * 16 + reg) * NPAD + cb + NF * 16] = A[reg];   \
  }
  STORE_ACC(a00, 0, 0) STORE_ACC(a01, 0, 1) STORE_ACC(a10, 1, 0) STORE_ACC(a11, 1, 1)
#undef STORE_ACC
}

// ---------------------------------------------------------------------------
// k_zh_mfma: per-step h-GEMM, bf16 MFMA, split-K=4 (K=128 per block).
//   zhp[kp][b, j] = h_bf[b, kp*128 ..] @ W[1024+kp*128 .., j]
// Single LDS stage (whole K=128 tile), ONE barrier, 16 straight MFMAs.
// grid (NPAD/64, BATCH/64, KSH), block 256
// ---------------------------------------------------------------------------
__global__ void __launch_bounds__(256)
k_zh_mfma(const u16* __restrict__ h_bf,
          const u16* __restrict__ W_bt,
          float* __restrict__ zhp) {
  __shared__ u16 Asb[64][136];   // pad 136: 272B row stride -> 2-way (free)
  __shared__ u16 Bsb[64][136];
  const int tid  = threadIdx.x;
  const int lane = tid & 63;
  const int wid  = tid >> 6;
  const int wm   = wid >> 1, wn = wid & 1;
  const int j0 = blockIdx.x * 64;
  const int r0 = blockIdx.y * 64;
  const int kp = blockIdx.z;
  const int srow = tid >> 2;          // 0..63
  const int sseg = (tid & 3) * 32;    // 4 segs x 32 k
  const u16* arow = &h_bf[(size_t)(r0 + srow) * D_H + kp * 128 + sseg];
  const u16* brow = &W_bt[(size_t)(j0 + srow) * KTOT + D_IN + kp * 128 + sseg];

  #pragma unroll
  for (int i = 0; i < 4; ++i) {
    *reinterpret_cast<s16x8*>(&Asb[srow][sseg + i * 8]) =
        *reinterpret_cast<const s16x8*>(&arow[i * 8]);
    *reinterpret_cast<s16x8*>(&Bsb[srow][sseg + i * 8]) =
        *reinterpret_cast<const s16x8*>(&brow[i * 8]);
  }
  __syncthreads();

  f32x4 a00 = {0.f, 0.f, 0.f, 0.f}, a01 = {0.f, 0.f, 0.f, 0.f};
  f32x4 a10 = {0.f, 0.f, 0.f, 0.f}, a11 = {0.f, 0.f, 0.f, 0.f};
  const int la = lane & 15;
  #pragma unroll
  for (int kk = 0; kk < 4; ++kk) {
    const int ka = kk * 32 + (lane >> 4) * 8;
    const s16x8 af0 = *reinterpret_cast<s16x8*>(&Asb[wm * 32 + la][ka]);
    const s16x8 af1 = *reinterpret_cast<s16x8*>(&Asb[wm * 32 + 16 + la][ka]);
    const s16x8 bf0 = *reinterpret_cast<s16x8*>(&Bsb[wn * 32 + la][ka]);
    const s16x8 bf1 = *reinterpret_cast<s16x8*>(&Bsb[wn * 32 + 16 + la][ka]);
    a00 = __builtin_amdgcn_mfma_f32_16x16x32_bf16(af0, bf0, a00, 0, 0, 0);
    a01 = __builtin_amdgcn_mfma_f32_16x16x32_bf16(af0, bf1, a01, 0, 0, 0);
    a10 = __builtin_amdgcn_mfma_f32_16x16x32_bf16(af1, bf0, a10, 0, 0, 0);
    a11 = __builtin_amdgcn_mfma_f32_16x16x32_bf16(af1, bf1, a11, 0, 0, 0);
  }
  const int rb = r0 + wm * 32 + (lane >> 4) * 4;
  const int cb = j0 + wn * 32 + (lane & 15);
  float* zp = &zhp[(size_t)kp * BATCH * NPAD];
#define STORE_ACC(A, MF, NF)                                             \
  {                                                                      \
    _Pragma("unroll")                                                    \
    for (int reg = 0; reg < 4; ++reg)                                    \
      zp[(size_t)(rb + MF * 16 + reg) * NPAD + cb + NF * 16] = A[reg];   \
  }
  STORE_ACC(a00, 0, 0) STORE_ACC(a01, 0, 1) STORE_ACC(a10, 1, 0) STORE_ACC(a11, 1, 1)
#undef STORE_ACC
}

// ---------------------------------------------------------------------------
// k_phase2: softmaxes, c, cw=c@Wrh(bf16), M2(bf16) RMW + racc, h'=relu(...).
// grid (D_H/128, BATCH/2), block 512 = 8 waves.
// M2 values are PREFETCHED into registers before the cw phase; the post-cw
// __syncthreads (vmcnt(0) drain) guarantees they've landed before the blend.
// ---------------------------------------------------------------------------
__global__ void __launch_bounds__(512)
k_phase2(const float* __restrict__ zx,
         const float* __restrict__ zhp,
         const u16* __restrict__ Wrh_bf,
         const float* __restrict__ b_rp,
         const float* __restrict__ b_wp,
         const float* __restrict__ b_c,
         const float* __restrict__ bh,
         u16* __restrict__ M2b,
         float* __restrict__ out,
         u16* __restrict__ h_bf,
         int t, int tc, int CH, int T) {
  __shared__ float ar_s[2][M_BANK];
  __shared__ float aw_s[2][M_BANK];
  __shared__ float c_s[2][D_H];
  __shared__ float red[2][16][32][4];   // 16 KB
  __shared__ float smx[2][2][2];
  __shared__ float ssm[2][2][2];
  const int tid  = threadIdx.x;
  const int ba   = tid >> 8;            // batch-half 0/1
  const int lane = tid & 31;
  const int p    = blockIdx.x;          // col-slice 0..3
  const int b0   = blockIdx.y * 2;
  const int b_g  = b0 + ba;
  const int s0   = p * 128 + lane * 4;
  const bool hz  = (t > 0);
  const size_t zxrow = (size_t)(b_g * CH + tc) * NPAD;

  // ---- softmaxes, fully parallel: u=tid&255, which=u>>7, m=u&127
  {
    const int u     = tid & 255;
    const int which = u >> 7;
    const int m     = u & 127;
    const int wv    = (u >> 6) & 1;     // wave within which-half
    float l = -1e30f;
    if (m < M_BANK) {
      const int col = which * 100 + m;
      l = (which ? b_wp[m] : b_rp[m]) + zx[zxrow + col];
      if (hz) {
        #pragma unroll
        for (int q = 0; q < KSH; ++q)
          l += zhp[(size_t)(q * BATCH + b_g) * NPAD + col];
      }
    }
    float mx = l;
    #pragma unroll
    for (int o = 32; o; o >>= 1) mx = fmaxf(mx, __shfl_xor(mx, o, 64));
    if ((tid & 63) == 0) smx[ba][which][wv] = mx;
    __syncthreads();
    mx = fmaxf(smx[ba][which][0], smx[ba][which][1]);
    const float e = (m < M_BANK) ? __expf(l - mx) : 0.f;
    float s = e;
    #pragma unroll
    for (int o = 32; o; o >>= 1) s += __shfl_xor(s, o, 64);
    if ((tid & 63) == 0) ssm[ba][which][wv] = s;
    __syncthreads();
    s = ssm[ba][which][0] + ssm[ba][which][1];
    if (m < M_BANK) {
      const float a = e / s;
      if (which) aw_s[ba][m] = a;
      else       ar_s[ba][m] = a;
    }
  }
  // ---- stage c = relu(zc + b_c) for the block's 2 batches (2 elems/thread)
  for (int idx = tid; idx < 2 * D_H; idx += 512) {
    const int bb  = idx >> 9;
    const int k   = idx & 511;
    const int bg2 = b0 + bb;
    float v = b_c[k] + zx[(size_t)(bg2 * CH + tc) * NPAD + 200 + k];
    if (hz) {
      #pragma unroll
      for (int q = 0; q < KSH; ++q)
        v += zhp[(size_t)(q * BATCH + bg2) * NPAD + 200 + k];
    }
    c_s[bb][k] = fmaxf(v, 0.f);
  }
  __syncthreads();

  // ---- M2 PREFETCH: issue all RMW loads now; they drain at the post-cw
  //      barrier, hiding L2/L3 latency under the cw FMA stream.
  const int mg    = (tid >> 5) & 7;
  const int mcnt  = (mg < 4) ? 13 : 12;
  const int mbase = (mg < 4) ? mg * 13 : 52 + (mg - 4) * 12;
  u16* mp = &M2b[((size_t)b_g * M_BANK + mbase) * D_H + s0];
  ushort4 m2v[13];
  for (int mm = 0; mm < mcnt; ++mm)
    m2v[mm] = *reinterpret_cast<const ushort4*>(mp + (size_t)mm * D_H);

  // ---- cw partials: 16 k-groups of 32, both batches per Wrh(bf16) read
  {
    const int g = tid >> 5;             // 0..15
    float cwa[4] = {};
    float cwb[4] = {};
    const int kbase = g * 32;
    #pragma unroll 8
    for (int kk = 0; kk < 32; ++kk) {
      const int k = kbase + kk;
      const ushort4 w4 = *reinterpret_cast<const ushort4*>(&Wrh_bf[(size_t)k * D_H + s0]);
      const float w0 = bf2f(w4.x), w1 = bf2f(w4.y), w2 = bf2f(w4.z), w3 = bf2f(w4.w);
      const float ca = c_s[0][k];
      const float cb = c_s[1][k];
      cwa[0] += ca * w0; cwa[1] += ca * w1; cwa[2] += ca * w2; cwa[3] += ca * w3;
      cwb[0] += cb * w0; cwb[1] += cb * w1; cwb[2] += cb * w2; cwb[3] += cb * w3;
    }
    #pragma unroll
    for (int j = 0; j < 4; ++j) {
      red[0][g][lane][j] = cwa[j];
      red[1][g][lane][j] = cwb[j];
    }
  }
  __syncthreads();
  float cw[4] = {};
  #pragma unroll
  for (int gg = 0; gg < 16; ++gg)
    #pragma unroll
    for (int j = 0; j < 4; ++j) cw[j] += red[ba][gg][lane][j];
  __syncthreads();   // red reused for racc below

  // ---- M2 (bf16) blend + racc using prefetched values; store only
  float racc[4] = {};
  for (int mm = 0; mm < mcnt; ++mm) {
    const int m = mbase + mm;
    const ushort4 v4 = m2v[mm];
    const float v0 = bf2f(v4.x), v1 = bf2f(v4.y), v2 = bf2f(v4.z), v3 = bf2f(v4.w);
    const float a = ar_s[ba][m];
    const float w = aw_s[ba][m];
    racc[0] += a * v0; racc[1] += a * v1; racc[2] += a * v2; racc[3] += a * v3;
    ushort4 nv;
    nv.x = f2bf(w * cw[0] + (1.f - w) * v0);
    nv.y = f2bf(w * cw[1] + (1.f - w) * v1);
    nv.z = f2bf(w * cw[2] + (1.f - w) * v2);
    nv.w = f2bf(w * cw[3] + (1.f - w) * v3);
    *reinterpret_cast<ushort4*>(mp + (size_t)mm * D_H) = nv;
  }
  #pragma unroll
  for (int j = 0; j < 4; ++j) red[ba][mg][lane][j] = racc[j];
  __syncthreads();

  // ---- h epilogue: 32 lanes per batch-half cover the 128-col slice
  if ((tid & 255) < 32) {
    float ph[4];
    const float4 vb = *reinterpret_cast<const float4*>(&bh[s0]);
    const float4 px = *reinterpret_cast<const float4*>(&zx[zxrow + 712 + s0]);
    ph[0] = vb.x + px.x; ph[1] = vb.y + px.y;
    ph[2] = vb.z + px.z; ph[3] = vb.w + px.w;
    #pragma unroll
    for (int gg = 0; gg < 8; ++gg)
      #pragma unroll
      for (int j = 0; j < 4; ++j) ph[j] += red[ba][gg][lane][j];
    if (hz) {
      #pragma unroll
      for (int q = 0; q < KSH; ++q) {
        const float4 pz = *reinterpret_cast<const float4*>(
            &zhp[(size_t)(q * BATCH + b_g) * NPAD + 712 + s0]);
        ph[0] += pz.x; ph[1] += pz.y; ph[2] += pz.z; ph[3] += pz.w;
      }
    }
    float4 h;
    h.x = fmaxf(ph[0], 0.f); h.y = fmaxf(ph[1], 0.f);
    h.z = fmaxf(ph[2], 0.f); h.w = fmaxf(ph[3], 0.f);
    *reinterpret_cast<float4*>(&out[((size_t)b_g * T + t) * D_H + s0]) = h;
    ushort4 hb;
    hb.x = f2bf(h.x); hb.y = f2bf(h.y); hb.z = f2bf(h.z); hb.w = f2bf(h.w);
    *reinterpret_cast<ushort4*>(&h_bf[(size_t)b_g * D_H + s0]) = hb;
  }
}

// ---------------------------------------------------------------------------
extern "C" void kernel_launch(void* const* d_in, const int* in_sizes, int n_in,
                              void* d_out, int out_size, void* d_ws, size_t ws_size,
                              hipStream_t stream) {
  const float* frames = (const float*)d_in[0];
  const float* W_c    = (const float*)d_in[1];
  const float* b_c    = (const float*)d_in[2];
  const float* W_rp   = (const float*)d_in[3];
  const float* b_rp   = (const float*)d_in[4];
  const float* W_wp   = (const float*)d_in[5];
  const float* b_wp   = (const float*)d_in[6];
  const float* Wxh    = (const float*)d_in[7];
  const float* Wrh    = (const float*)d_in[8];
  const float* Whh    = (const float*)d_in[9];
  const float* bh     = (const float*)d_in[10];
  float* out = (float*)d_out;

  const int TF = in_sizes[0] / (BATCH * D_IN);
  const int T  = out_size / (BATCH * D_H);

  // element counts in float-equivalents (u16 regions counted /2)
  const size_t M2B_FL   = (size_t)BATCH * M_BANK * D_H / 2;   // bf16 M2: 13.1 MB
  const size_t ZHP_FL   = (size_t)KSH * BATCH * NPAD;         // 2.6 MB
  const size_t WBT_FL   = (size_t)NPAD * KTOT / 2;            // 3.9 MB
  const size_t WRH_FL   = (size_t)D_H * D_H / 2;              // 0.5 MB
  const size_t HBF_FL   = (size_t)BATCH * D_H / 2;            // 0.13 MB

  u16*   M2b = (u16*)d_ws;
  float* zhp = (float*)d_ws + M2B_FL;
  float* zx  = zhp + ZHP_FL;

  int CH = 64, lgCH = 6;
  while (CH > 1 &&
         ((M2B_FL + ZHP_FL + WBT_FL + WRH_FL + HBF_FL +
           (size_t)BATCH * CH * NPAD) * sizeof(float) > ws_size ||
          (T % CH) != 0)) {
    CH >>= 1; --lgCH;
  }

  u16* W_bt   = (u16*)(zx + (size_t)BATCH * CH * NPAD);
  u16* Wrh_bf = W_bt + (size_t)NPAD * KTOT;
  u16* h_bf   = Wrh_bf + (size_t)D_H * D_H;

  hipMemsetAsync(M2b, 0, M2B_FL * sizeof(float), stream);
  k_prep_w<<<dim3(NPAD, KTOT / 256), 256, 0, stream>>>(W_c, W_rp, W_wp, Wxh, Whh, W_bt);
  k_prep_wrh<<<dim3(D_H * D_H / 256), 256, 0, stream>>>(Wrh, Wrh_bf);

  for (int t0 = 0; t0 < T; t0 += CH) {
    k_zx_mfma<<<dim3(NPAD / 64, BATCH * CH / 64), 256, 0, stream>>>(
        frames, W_bt, zx, t0, CH, lgCH, TF);
    for (int t = t0; t < t0 + CH; ++t) {
      if (t > 0)
        k_zh_mfma<<<dim3(NPAD / 64, BATCH / 64, KSH), 256, 0, stream>>>(h_bf, W_bt, zhp);
      k_phase2<<<dim3(D_H / 128, BATCH / 2), 512, 0, stream>>>(
          zx, zhp, Wrh_bf, b_rp, b_wp, b_c, bh, M2b, out, h_bf, t, t - t0, CH, T);
    }
  }
}

// Round 12
// 4234.471 us; speedup vs baseline: 2.1573x; 1.4355x over previous
//
#include <hip/hip_runtime.h>

#define D_IN   1024
#define D_H    512
#define M_BANK 100
#define BATCH  128
#define NCOL   1224   // 100 rp | 100 wp | 512 c | 512 pre_h
#define NPAD   1280
#define KTOT   1536
#define KSH    4      // split-K partials for the per-step h-GEMM

typedef unsigned short u16;
typedef __attribute__((ext_vector_type(8))) short s16x8;
typedef __attribute__((ext_vector_type(4))) float f32x4;

__device__ __forceinline__ u16 f2bf(float f) {
  union { float f; unsigned int u; } v;
  v.f = f;
  unsigned int r = (v.u + 0x7FFFu + ((v.u >> 16) & 1u)) >> 16;
  return (u16)r;
}
__device__ __forceinline__ float bf2f(u16 b) {
  union { unsigned int u; float f; } v;
  v.u = ((unsigned int)b) << 16;
  return v.f;
}

// ---------------------------------------------------------------------------
// k_prep_w: W_bt[j][k] = bf16 of composite W[k][j]  (j-major, for MFMA B-stage)
//   cols [0,100)=W_rp [100,200)=W_wp [200,712)=W_c [712,1224)=Wxh/Whh else 0
// ---------------------------------------------------------------------------
__global__ void k_prep_w(const float* __restrict__ W_c,
                         const float* __restrict__ W_rp,
                         const float* __restrict__ W_wp,
                         const float* __restrict__ Wxh,
                         const float* __restrict__ Whh,
                         u16* __restrict__ W_bt) {
  const int j = blockIdx.x;
  const int k = blockIdx.y * 256 + threadIdx.x;
  float v = 0.f;
  if (j < 100)       v = W_rp[(size_t)k * M_BANK + j];
  else if (j < 200)  v = W_wp[(size_t)k * M_BANK + (j - 100)];
  else if (j < 712)  v = W_c[(size_t)k * D_H + (j - 200)];
  else if (j < NCOL) v = (k < D_IN) ? Wxh[(size_t)k * D_H + (j - 712)]
                                    : Whh[(size_t)(k - D_IN) * D_H + (j - 712)];
  W_bt[(size_t)j * KTOT + k] = f2bf(v);
}

__global__ void k_prep_wrh(const float* __restrict__ Wrh,
                           u16* __restrict__ Wrh_bf) {
  const int i = blockIdx.x * 256 + threadIdx.x;
  Wrh_bf[i] = f2bf(Wrh[i]);
}

// ---------------------------------------------------------------------------
// k_zx_mfma: hoisted x-GEMM, bf16 MFMA. zx[(b*CH+tc), j] = x @ W[0:1024, j]
// grid (NPAD/64, BATCH*CH/64), block 256 = 4 waves (2x2 of 32x32)
// ---------------------------------------------------------------------------
__global__ void k_zx_mfma(const float* __restrict__ frames,
                          const u16* __restrict__ W_bt,
                          float* __restrict__ zx,
                          int t0, int CH, int lgCH, int TF) {
  __shared__ u16 Asb[64][40];
  __shared__ u16 Bsb[64][40];
  const int tid  = threadIdx.x;
  const int lane = tid & 63;
  const int wid  = tid >> 6;
  const int wm   = wid >> 1, wn = wid & 1;
  const int j0 = blockIdx.x * 64;
  const int r0 = blockIdx.y * 64;
  const int srow = tid >> 2;
  const int skk  = (tid & 3) * 8;
  const int gr = r0 + srow;
  const int b  = gr >> lgCH;
  const int tc = gr & (CH - 1);
  const float* arow = &frames[((size_t)b * TF + t0 + tc) * D_IN];
  const u16*   brow = &W_bt[(size_t)(j0 + srow) * KTOT];

  f32x4 a00 = {0.f, 0.f, 0.f, 0.f}, a01 = {0.f, 0.f, 0.f, 0.f};
  f32x4 a10 = {0.f, 0.f, 0.f, 0.f}, a11 = {0.f, 0.f, 0.f, 0.f};

  for (int k0 = 0; k0 < D_IN; k0 += 32) {
    const float4 v0 = *reinterpret_cast<const float4*>(&arow[k0 + skk]);
    const float4 v1 = *reinterpret_cast<const float4*>(&arow[k0 + skk + 4]);
    s16x8 a8;
    a8[0] = (short)f2bf(v0.x); a8[1] = (short)f2bf(v0.y);
    a8[2] = (short)f2bf(v0.z); a8[3] = (short)f2bf(v0.w);
    a8[4] = (short)f2bf(v1.x); a8[5] = (short)f2bf(v1.y);
    a8[6] = (short)f2bf(v1.z); a8[7] = (short)f2bf(v1.w);
    *reinterpret_cast<s16x8*>(&Asb[srow][skk]) = a8;
    *reinterpret_cast<s16x8*>(&Bsb[srow][skk]) =
        *reinterpret_cast<const s16x8*>(&brow[k0 + skk]);
    __syncthreads();
    const int ka = (lane >> 4) * 8;
    const s16x8 af0 = *reinterpret_cast<s16x8*>(&Asb[wm * 32 + (lane & 15)][ka]);
    const s16x8 af1 = *reinterpret_cast<s16x8*>(&Asb[wm * 32 + 16 + (lane & 15)][ka]);
    const s16x8 bf0 = *reinterpret_cast<s16x8*>(&Bsb[wn * 32 + (lane & 15)][ka]);
    const s16x8 bf1 = *reinterpret_cast<s16x8*>(&Bsb[wn * 32 + 16 + (lane & 15)][ka]);
    a00 = __builtin_amdgcn_mfma_f32_16x16x32_bf16(af0, bf0, a00, 0, 0, 0);
    a01 = __builtin_amdgcn_mfma_f32_16x16x32_bf16(af0, bf1, a01, 0, 0, 0);
    a10 = __builtin_amdgcn_mfma_f32_16x16x32_bf16(af1, bf0, a10, 0, 0, 0);
    a11 = __builtin_amdgcn_mfma_f32_16x16x32_bf16(af1, bf1, a11, 0, 0, 0);
    __syncthreads();
  }
  const int rb = r0 + wm * 32 + (lane >> 4) * 4;
  const int cb = j0 + wn * 32 + (lane & 15);
#define STORE_ACC(A, MF, NF)                                             \
  {                                                                      \
    _Pragma("unroll")                                                    \
    for (int reg = 0; reg < 4; ++reg)                                    \
      zx[(size_t)(rb + MF * 16 + reg) * NPAD + cb + NF * 16] = A[reg];   \
  }
  STORE_ACC(a00, 0, 0) STORE_ACC(a01, 0, 1) STORE_ACC(a10, 1, 0) STORE_ACC(a11, 1, 1)
#undef STORE_ACC
}

// ---------------------------------------------------------------------------
// k_zh_mfma: per-step h-GEMM, bf16 MFMA, split-K=4 (K=128 per block).
//   zhp[kp][b, j] = h_bf[b, kp*128 ..] @ W[1024+kp*128 .., j]
// Single LDS stage (whole K=128 tile), ONE barrier, 16 straight MFMAs.
// grid (NPAD/64, BATCH/64, KSH), block 256
// ---------------------------------------------------------------------------
__global__ void __launch_bounds__(256)
k_zh_mfma(const u16* __restrict__ h_bf,
          const u16* __restrict__ W_bt,
          float* __restrict__ zhp) {
  __shared__ u16 Asb[64][136];   // pad 136: 272B row stride -> 2-way (free)
  __shared__ u16 Bsb[64][136];
  const int tid  = threadIdx.x;
  const int lane = tid & 63;
  const int wid  = tid >> 6;
  const int wm   = wid >> 1, wn = wid & 1;
  const int j0 = blockIdx.x * 64;
  const int r0 = blockIdx.y * 64;
  const int kp = blockIdx.z;
  const int srow = tid >> 2;          // 0..63
  const int sseg = (tid & 3) * 32;    // 4 segs x 32 k
  const u16* arow = &h_bf[(size_t)(r0 + srow) * D_H + kp * 128 + sseg];
  const u16* brow = &W_bt[(size_t)(j0 + srow) * KTOT + D_IN + kp * 128 + sseg];

  #pragma unroll
  for (int i = 0; i < 4; ++i) {
    *reinterpret_cast<s16x8*>(&Asb[srow][sseg + i * 8]) =
        *reinterpret_cast<const s16x8*>(&arow[i * 8]);
    *reinterpret_cast<s16x8*>(&Bsb[srow][sseg + i * 8]) =
        *reinterpret_cast<const s16x8*>(&brow[i * 8]);
  }
  __syncthreads();

  f32x4 a00 = {0.f, 0.f, 0.f, 0.f}, a01 = {0.f, 0.f, 0.f, 0.f};
  f32x4 a10 = {0.f, 0.f, 0.f, 0.f}, a11 = {0.f, 0.f, 0.f, 0.f};
  const int la = lane & 15;
  #pragma unroll
  for (int kk = 0; kk < 4; ++kk) {
    const int ka = kk * 32 + (lane >> 4) * 8;
    const s16x8 af0 = *reinterpret_cast<s16x8*>(&Asb[wm * 32 + la][ka]);
    const s16x8 af1 = *reinterpret_cast<s16x8*>(&Asb[wm * 32 + 16 + la][ka]);
    const s16x8 bf0 = *reinterpret_cast<s16x8*>(&Bsb[wn * 32 + la][ka]);
    const s16x8 bf1 = *reinterpret_cast<s16x8*>(&Bsb[wn * 32 + 16 + la][ka]);
    a00 = __builtin_amdgcn_mfma_f32_16x16x32_bf16(af0, bf0, a00, 0, 0, 0);
    a01 = __builtin_amdgcn_mfma_f32_16x16x32_bf16(af0, bf1, a01, 0, 0, 0);
    a10 = __builtin_amdgcn_mfma_f32_16x16x32_bf16(af1, bf0, a10, 0, 0, 0);
    a11 = __builtin_amdgcn_mfma_f32_16x16x32_bf16(af1, bf1, a11, 0, 0, 0);
  }
  const int rb = r0 + wm * 32 + (lane >> 4) * 4;
  const int cb = j0 + wn * 32 + (lane & 15);
  float* zp = &zhp[(size_t)kp * BATCH * NPAD];
#define STORE_ACC(A, MF, NF)                                             \
  {                                                                      \
    _Pragma("unroll")                                                    \
    for (int reg = 0; reg < 4; ++reg)                                    \
      zp[(size_t)(rb + MF * 16 + reg) * NPAD + cb + NF * 16] = A[reg];   \
  }
  STORE_ACC(a00, 0, 0) STORE_ACC(a01, 0, 1) STORE_ACC(a10, 1, 0) STORE_ACC(a11, 1, 1)
#undef STORE_ACC
}

// ---------------------------------------------------------------------------
// k_phase2: softmaxes, c, cw=c@Wrh(bf16), M2(bf16) RMW + racc, h'=relu(...).
// grid (D_H/128, BATCH/2), block 512 = 8 waves.
// M2 prefetch: COMPILE-TIME unrolled (trip 13, predicated) so m2v stays in
// VGPRs (runtime-bounded loop would spill to scratch — R11 lesson).
// ---------------------------------------------------------------------------
__global__ void __launch_bounds__(512)
k_phase2(const float* __restrict__ zx,
         const float* __restrict__ zhp,
         const u16* __restrict__ Wrh_bf,
         const float* __restrict__ b_rp,
         const float* __restrict__ b_wp,
         const float* __restrict__ b_c,
         const float* __restrict__ bh,
         u16* __restrict__ M2b,
         float* __restrict__ out,
         u16* __restrict__ h_bf,
         int t, int tc, int CH, int T) {
  __shared__ float ar_s[2][M_BANK];
  __shared__ float aw_s[2][M_BANK];
  __shared__ float c_s[2][D_H];
  __shared__ float red[2][16][32][4];   // 16 KB
  __shared__ float smx[2][2][2];
  __shared__ float ssm[2][2][2];
  const int tid  = threadIdx.x;
  const int ba   = tid >> 8;            // batch-half 0/1
  const int lane = tid & 31;
  const int p    = blockIdx.x;          // col-slice 0..3
  const int b0   = blockIdx.y * 2;
  const int b_g  = b0 + ba;
  const int s0   = p * 128 + lane * 4;
  const bool hz  = (t > 0);
  const size_t zxrow = (size_t)(b_g * CH + tc) * NPAD;

  // ---- softmaxes, fully parallel: u=tid&255, which=u>>7, m=u&127
  {
    const int u     = tid & 255;
    const int which = u >> 7;
    const int m     = u & 127;
    const int wv    = (u >> 6) & 1;     // wave within which-half
    float l = -1e30f;
    if (m < M_BANK) {
      const int col = which * 100 + m;
      l = (which ? b_wp[m] : b_rp[m]) + zx[zxrow + col];
      if (hz) {
        #pragma unroll
        for (int q = 0; q < KSH; ++q)
          l += zhp[(size_t)(q * BATCH + b_g) * NPAD + col];
      }
    }
    float mx = l;
    #pragma unroll
    for (int o = 32; o; o >>= 1) mx = fmaxf(mx, __shfl_xor(mx, o, 64));
    if ((tid & 63) == 0) smx[ba][which][wv] = mx;
    __syncthreads();
    mx = fmaxf(smx[ba][which][0], smx[ba][which][1]);
    const float e = (m < M_BANK) ? __expf(l - mx) : 0.f;
    float s = e;
    #pragma unroll
    for (int o = 32; o; o >>= 1) s += __shfl_xor(s, o, 64);
    if ((tid & 63) == 0) ssm[ba][which][wv] = s;
    __syncthreads();
    s = ssm[ba][which][0] + ssm[ba][which][1];
    if (m < M_BANK) {
      const float a = e / s;
      if (which) aw_s[ba][m] = a;
      else       ar_s[ba][m] = a;
    }
  }
  // ---- stage c = relu(zc + b_c) for the block's 2 batches (2 elems/thread)
  for (int idx = tid; idx < 2 * D_H; idx += 512) {
    const int bb  = idx >> 9;
    const int k   = idx & 511;
    const int bg2 = b0 + bb;
    float v = b_c[k] + zx[(size_t)(bg2 * CH + tc) * NPAD + 200 + k];
    if (hz) {
      #pragma unroll
      for (int q = 0; q < KSH; ++q)
        v += zhp[(size_t)(q * BATCH + bg2) * NPAD + 200 + k];
    }
    c_s[bb][k] = fmaxf(v, 0.f);
  }
  __syncthreads();

  // ---- M2 PREFETCH (registers): compile-time trip 13, predicated.
  const int mg    = (tid >> 5) & 7;
  const int mcnt  = (mg < 4) ? 13 : 12;
  const int mbase = (mg < 4) ? mg * 13 : 52 + (mg - 4) * 12;
  u16* mp = &M2b[((size_t)b_g * M_BANK + mbase) * D_H + s0];
  ushort4 m2v[13];
  #pragma unroll
  for (int mm = 0; mm < 13; ++mm)
    if (mm < mcnt)
      m2v[mm] = *reinterpret_cast<const ushort4*>(mp + (size_t)mm * D_H);

  // ---- cw partials: 16 k-groups of 32, both batches per Wrh(bf16) read
  {
    const int g = tid >> 5;             // 0..15
    float cwa[4] = {};
    float cwb[4] = {};
    const int kbase = g * 32;
    #pragma unroll 8
    for (int kk = 0; kk < 32; ++kk) {
      const int k = kbase + kk;
      const ushort4 w4 = *reinterpret_cast<const ushort4*>(&Wrh_bf[(size_t)k * D_H + s0]);
      const float w0 = bf2f(w4.x), w1 = bf2f(w4.y), w2 = bf2f(w4.z), w3 = bf2f(w4.w);
      const float ca = c_s[0][k];
      const float cb = c_s[1][k];
      cwa[0] += ca * w0; cwa[1] += ca * w1; cwa[2] += ca * w2; cwa[3] += ca * w3;
      cwb[0] += cb * w0; cwb[1] += cb * w1; cwb[2] += cb * w2; cwb[3] += cb * w3;
    }
    #pragma unroll
    for (int j = 0; j < 4; ++j) {
      red[0][g][lane][j] = cwa[j];
      red[1][g][lane][j] = cwb[j];
    }
  }
  __syncthreads();
  float cw[4] = {};
  #pragma unroll
  for (int gg = 0; gg < 16; ++gg)
    #pragma unroll
    for (int j = 0; j < 4; ++j) cw[j] += red[ba][gg][lane][j];
  __syncthreads();   // red reused for racc below

  // ---- M2 (bf16) blend + racc using prefetched registers; store only
  float racc[4] = {};
  #pragma unroll
  for (int mm = 0; mm < 13; ++mm) {
    if (mm < mcnt) {
      const int m = mbase + mm;
      const ushort4 v4 = m2v[mm];
      const float v0 = bf2f(v4.x), v1 = bf2f(v4.y), v2 = bf2f(v4.z), v3 = bf2f(v4.w);
      const float a = ar_s[ba][m];
      const float w = aw_s[ba][m];
      racc[0] += a * v0; racc[1] += a * v1; racc[2] += a * v2; racc[3] += a * v3;
      ushort4 nv;
      nv.x = f2bf(w * cw[0] + (1.f - w) * v0);
      nv.y = f2bf(w * cw[1] + (1.f - w) * v1);
      nv.z = f2bf(w * cw[2] + (1.f - w) * v2);
      nv.w = f2bf(w * cw[3] + (1.f - w) * v3);
      *reinterpret_cast<ushort4*>(mp + (size_t)mm * D_H) = nv;
    }
  }
  #pragma unroll
  for (int j = 0; j < 4; ++j) red[ba][mg][lane][j] = racc[j];
  __syncthreads();

  // ---- h epilogue: 32 lanes per batch-half cover the 128-col slice
  if ((tid & 255) < 32) {
    float ph[4];
    const float4 vb = *reinterpret_cast<const float4*>(&bh[s0]);
    const float4 px = *reinterpret_cast<const float4*>(&zx[zxrow + 712 + s0]);
    ph[0] = vb.x + px.x; ph[1] = vb.y + px.y;
    ph[2] = vb.z + px.z; ph[3] = vb.w + px.w;
    #pragma unroll
    for (int gg = 0; gg < 8; ++gg)
      #pragma unroll
      for (int j = 0; j < 4; ++j) ph[j] += red[ba][gg][lane][j];
    if (hz) {
      #pragma unroll
      for (int q = 0; q < KSH; ++q) {
        const float4 pz = *reinterpret_cast<const float4*>(
            &zhp[(size_t)(q * BATCH + b_g) * NPAD + 712 + s0]);
        ph[0] += pz.x; ph[1] += pz.y; ph[2] += pz.z; ph[3] += pz.w;
      }
    }
    float4 h;
    h.x = fmaxf(ph[0], 0.f); h.y = fmaxf(ph[1], 0.f);
    h.z = fmaxf(ph[2], 0.f); h.w = fmaxf(ph[3], 0.f);
    *reinterpret_cast<float4*>(&out[((size_t)b_g * T + t) * D_H + s0]) = h;
    ushort4 hb;
    hb.x = f2bf(h.x); hb.y = f2bf(h.y); hb.z = f2bf(h.z); hb.w = f2bf(h.w);
    *reinterpret_cast<ushort4*>(&h_bf[(size_t)b_g * D_H + s0]) = hb;
  }
}

// ---------------------------------------------------------------------------
extern "C" void kernel_launch(void* const* d_in, const int* in_sizes, int n_in,
                              void* d_out, int out_size, void* d_ws, size_t ws_size,
                              hipStream_t stream) {
  const float* frames = (const float*)d_in[0];
  const float* W_c    = (const float*)d_in[1];
  const float* b_c    = (const float*)d_in[2];
  const float* W_rp   = (const float*)d_in[3];
  const float* b_rp   = (const float*)d_in[4];
  const float* W_wp   = (const float*)d_in[5];
  const float* b_wp   = (const float*)d_in[6];
  const float* Wxh    = (const float*)d_in[7];
  const float* Wrh    = (const float*)d_in[8];
  const float* Whh    = (const float*)d_in[9];
  const float* bh     = (const float*)d_in[10];
  float* out = (float*)d_out;

  const int TF = in_sizes[0] / (BATCH * D_IN);
  const int T  = out_size / (BATCH * D_H);

  // element counts in float-equivalents (u16 regions counted /2)
  const size_t M2B_FL   = (size_t)BATCH * M_BANK * D_H / 2;   // bf16 M2: 13.1 MB
  const size_t ZHP_FL   = (size_t)KSH * BATCH * NPAD;         // 2.6 MB
  const size_t WBT_FL   = (size_t)NPAD * KTOT / 2;            // 3.9 MB
  const size_t WRH_FL   = (size_t)D_H * D_H / 2;              // 0.5 MB
  const size_t HBF_FL   = (size_t)BATCH * D_H / 2;            // 0.13 MB

  u16*   M2b = (u16*)d_ws;
  float* zhp = (float*)d_ws + M2B_FL;
  float* zx  = zhp + ZHP_FL;

  int CH = 64, lgCH = 6;
  while (CH > 1 &&
         ((M2B_FL + ZHP_FL + WBT_FL + WRH_FL + HBF_FL +
           (size_t)BATCH * CH * NPAD) * sizeof(float) > ws_size ||
          (T % CH) != 0)) {
    CH >>= 1; --lgCH;
  }

  u16* W_bt   = (u16*)(zx + (size_t)BATCH * CH * NPAD);
  u16* Wrh_bf = W_bt + (size_t)NPAD * KTOT;
  u16* h_bf   = Wrh_bf + (size_t)D_H * D_H;

  hipMemsetAsync(M2b, 0, M2B_FL * sizeof(float), stream);
  k_prep_w<<<dim3(NPAD, KTOT / 256), 256, 0, stream>>>(W_c, W_rp, W_wp, Wxh, Whh, W_bt);
  k_prep_wrh<<<dim3(D_H * D_H / 256), 256, 0, stream>>>(Wrh, Wrh_bf);

  for (int t0 = 0; t0 < T; t0 += CH) {
    k_zx_mfma<<<dim3(NPAD / 64, BATCH * CH / 64), 256, 0, stream>>>(
        frames, W_bt, zx, t0, CH, lgCH, TF);
    for (int t = t0; t < t0 + CH; ++t) {
      if (t > 0)
        k_zh_mfma<<<dim3(NPAD / 64, BATCH / 64, KSH), 256, 0, stream>>>(h_bf, W_bt, zhp);
      k_phase2<<<dim3(D_H / 128, BATCH / 2), 512, 0, stream>>>(
          zx, zhp, Wrh_bf, b_rp, b_wp, b_c, bh, M2b, out, h_bf, t, t - t0, CH, T);
    }
  }
}